// Round 2
// baseline (1000.178 us; speedup 1.0000x reference)
//
#include <hip/hip_runtime.h>
#include <hip/hip_bf16.h>
#include <stdint.h>

#define T_SEQ 2048
#define HID   4096
#define NQKV  12288
#define NH    32
#define HD    128

typedef __attribute__((ext_vector_type(8))) short bf16x8;
typedef __attribute__((ext_vector_type(4))) float f32x4;

__device__ __forceinline__ unsigned short f2b(float f) {
    __hip_bfloat16 h = __float2bfloat16(f);
    return *reinterpret_cast<unsigned short*>(&h);
}
__device__ __forceinline__ unsigned int pack2(float a, float b) {
    return (unsigned int)f2b(a) | ((unsigned int)f2b(b) << 16);
}
__device__ __forceinline__ f32x4 mfma16(bf16x8 a, bf16x8 b, f32x4 c) {
    return __builtin_amdgcn_mfma_f32_16x16x32_bf16(a, b, c, 0, 0, 0);
}
__device__ __forceinline__ void gld_lds16(const void* g, void* l) {
    __builtin_amdgcn_global_load_lds(
        (const __attribute__((address_space(1))) unsigned int*)g,
        (__attribute__((address_space(3))) unsigned int*)l, 16, 0, 0);
}

// ---------------- cast fp32 -> bf16, 4 elems/thread ----------------
__global__ __launch_bounds__(256) void cast_f32_bf16(const float* __restrict__ src,
                                                     unsigned short* __restrict__ dst) {
    int i = (blockIdx.x * 256 + threadIdx.x) * 4;
    float4 v = *(const float4*)(src + i);
    ushort4 o;
    o.x = f2b(v.x); o.y = f2b(v.y); o.z = f2b(v.z); o.w = f2b(v.w);
    *(ushort4*)(dst + i) = o;
}

// ---------------- transpose: src fp32 [R][C] -> dst bf16 [C][R] ----------------
__global__ __launch_bounds__(256) void transpose_f32_bf16(const float* __restrict__ src,
                                                          unsigned short* __restrict__ dst,
                                                          int R, int C) {
    __shared__ float tile[64][65];
    int r0 = blockIdx.x * 64, c0 = blockIdx.y * 64;
    int tid = threadIdx.x;
#pragma unroll
    for (int i = 0; i < 4; i++) {
        int e = (tid + 256 * i) * 4;
        int r = e >> 6, c = e & 63;
        float4 v = *(const float4*)(src + (size_t)(r0 + r) * C + c0 + c);
        tile[r][c + 0] = v.x; tile[r][c + 1] = v.y;
        tile[r][c + 2] = v.z; tile[r][c + 3] = v.w;
    }
    __syncthreads();
#pragma unroll
    for (int i = 0; i < 4; i++) {
        int e = (tid + 256 * i) * 4;
        int rr = e >> 6, cc = e & 63;
        ushort4 o;
        o.x = f2b(tile[cc + 0][rr]); o.y = f2b(tile[cc + 1][rr]);
        o.z = f2b(tile[cc + 2][rr]); o.w = f2b(tile[cc + 3][rr]);
        *(ushort4*)(dst + (size_t)(c0 + rr) * R + r0 + cc) = o;
    }
}

// ---------------- deep-pipelined GEMM: C[M=2048][N] = A @ Bt^T (+bias) ----------------
// BM=256, BN=128, BK=32. 8 waves (4M x 2N), per-wave 64x64 output (4x4 16x16x32 frags).
// Ring-4 LDS K-tile buffers (96 KB), raw s_barrier (no vmcnt drain), counted vmcnt:
// prologue stages tiles 0..2; steady state keeps 2 tiles (6 loads/thread) in flight.
// T2: 16B-chunk XOR swizzle, applied on the GLOBAL source (gld_lds dest is lane-linear);
// fragment ds_read_b128 then covers a 1KB region bijectively -> conflict-free.
// T1: XCD map brow=id&7 -> each XCD owns one 2MB A-panel (fits its private L2).
template <int WITH_BIAS>
__global__ __launch_bounds__(512, 2) void gemm256(const unsigned short* __restrict__ A,
                                                  const unsigned short* __restrict__ Bt,
                                                  const float* __restrict__ bias,
                                                  float* __restrict__ C,
                                                  int N, int K) {
    __shared__ __align__(16) unsigned short As[4][256 * 32];  // 64 KB
    __shared__ __align__(16) unsigned short Bs[4][128 * 32];  // 32 KB
    int tid = threadIdx.x;
    int w = tid >> 6, lane = tid & 63;
    int quad = lane >> 4, cl = lane & 15;
    int wm = w >> 1, wn = w & 1;                 // 4 x 2 wave grid
    int id = blockIdx.x + gridDim.x * blockIdx.y;
    int brow = id & 7;                           // XCD-aligned row panel
    int bcol = id >> 3;
    const unsigned short* Ablk = A + (size_t)brow * 256 * K;
    const unsigned short* Bblk = Bt + (size_t)bcol * 128 * K;
    const int NT = K >> 5;

    // fragment LDS offsets (ushort units); swizzled chunk slot is lane-uniform across frags
    int slot = quad ^ ((cl >> 1) & 3);
    int aoff[4], boff[4];
#pragma unroll
    for (int f = 0; f < 4; f++) {
        aoff[f] = (wm * 64 + f * 16 + cl) * 32 + slot * 8;
        boff[f] = (wn * 64 + f * 16 + cl) * 32 + slot * 8;
    }

    f32x4 acc[4][4] = {};

    // stage K-tile t_: A = 1024 16B chunks (2/thread), B = 512 (1/thread)
#define STAGE(t_) do {                                                          \
        int k0 = (t_) * 32; int bs_ = (t_) & 3;                                 \
        _Pragma("unroll")                                                       \
        for (int j = 0; j < 2; j++) {                                           \
            int p = j * 512 + w * 64 + lane;                                    \
            int row = p >> 2;                                                   \
            int g = (p & 3) ^ ((row >> 1) & 3);                                 \
            gld_lds16(Ablk + (size_t)row * K + k0 + g * 8,                      \
                      &As[bs_][(j * 512 + w * 64) * 8]);                        \
        }                                                                       \
        {                                                                       \
            int p = w * 64 + lane;                                              \
            int row = p >> 2;                                                   \
            int g = (p & 3) ^ ((row >> 1) & 3);                                 \
            gld_lds16(Bblk + (size_t)row * K + k0 + g * 8,                      \
                      &Bs[bs_][(w * 64) * 8]);                                  \
        }                                                                       \
    } while (0)

#define GBODY(T, WAITS) do {                                                    \
        asm volatile("s_waitcnt " WAITS ::: "memory");                          \
        __builtin_amdgcn_s_barrier();                                           \
        asm volatile("" ::: "memory");                                          \
        if ((T) + 3 < NT) STAGE((T) + 3);                                       \
        const unsigned short* Ab = &As[(T) & 3][0];                             \
        const unsigned short* Bb = &Bs[(T) & 3][0];                             \
        bf16x8 af[4], bfv[4];                                                   \
        _Pragma("unroll")                                                       \
        for (int f = 0; f < 4; f++) af[f] = *(const bf16x8*)&Ab[aoff[f]];       \
        _Pragma("unroll")                                                       \
        for (int f = 0; f < 4; f++) bfv[f] = *(const bf16x8*)&Bb[boff[f]];      \
        __builtin_amdgcn_s_setprio(1);                                          \
        _Pragma("unroll")                                                       \
        for (int fi = 0; fi < 4; fi++)                                          \
            _Pragma("unroll")                                                   \
            for (int fj = 0; fj < 4; fj++)                                      \
                acc[fi][fj] = mfma16(af[fi], bfv[fj], acc[fi][fj]);             \
        __builtin_amdgcn_s_setprio(0);                                          \
    } while (0)

    STAGE(0); STAGE(1); STAGE(2);
    for (int t = 0; t < NT - 2; t++) {
        GBODY(t, "vmcnt(6)");     // retire tile t; tiles t+1,t+2 stay in flight
    }
    GBODY(NT - 2, "vmcnt(3)");
    GBODY(NT - 1, "vmcnt(0)");
#undef GBODY
#undef STAGE

    // epilogue: C/D frag layout col=cl, row=quad*4+r
#pragma unroll
    for (int fi = 0; fi < 4; fi++) {
        int row0 = brow * 256 + wm * 64 + fi * 16 + quad * 4;
#pragma unroll
        for (int fj = 0; fj < 4; fj++) {
            int col = bcol * 128 + wn * 64 + fj * 16 + cl;
            float bv = WITH_BIAS ? bias[col] : 0.f;
#pragma unroll
            for (int r = 0; r < 4; r++)
                C[(size_t)(row0 + r) * N + col] = acc[fi][fj][r] + bv;
        }
    }
}

// ---------------- RMSNorm (full 4096-dim) + RoPE -> bf16 q,k ----------------
__global__ __launch_bounds__(256) void rmsnorm_rope(const float* __restrict__ qkv,
                                                    const float* __restrict__ qw,
                                                    const float* __restrict__ kw,
                                                    unsigned short* __restrict__ qo,
                                                    unsigned short* __restrict__ ko) {
    int t = blockIdx.x, tid = threadIdx.x;
    const float* row = qkv + (size_t)t * NQKV;
    float sq = 0.f, sk = 0.f;
    for (int i = tid; i < HID; i += 256) {
        float x = row[i];        sq += x * x;
        float y = row[HID + i];  sk += y * y;
    }
#pragma unroll
    for (int off = 32; off > 0; off >>= 1) {
        sq += __shfl_xor(sq, off, 64);
        sk += __shfl_xor(sk, off, 64);
    }
    __shared__ float red[2][4];
    if ((tid & 63) == 0) { red[0][tid >> 6] = sq; red[1][tid >> 6] = sk; }
    __syncthreads();
    sq = red[0][0] + red[0][1] + red[0][2] + red[0][3];
    sk = red[1][0] + red[1][1] + red[1][2] + red[1][3];
    float rq = rsqrtf(sq * (1.0f / HID) + 1e-6f);
    float rk = rsqrtf(sk * (1.0f / HID) + 1e-6f);
    for (int p = tid; p < 2048; p += 256) {
        int h = p >> 6, d = p & 63;
        int c1 = h * 128 + d, c2 = c1 + 64;
        float inv = expf(-(float)d * 0.2158673524681918f);
        float ang = (float)t * inv;
        float sn, cs;
        sincosf(ang, &sn, &cs);
        float x1 = row[c1] * rq * qw[c1];
        float x2 = row[c2] * rq * qw[c2];
        qo[(size_t)t * HID + c1] = f2b(x1 * cs - x2 * sn);
        qo[(size_t)t * HID + c2] = f2b(x2 * cs + x1 * sn);
        float y1 = row[HID + c1] * rk * kw[c1];
        float y2 = row[HID + c2] * rk * kw[c2];
        ko[(size_t)t * HID + c1] = f2b(y1 * cs - y2 * sn);
        ko[(size_t)t * HID + c2] = f2b(y2 * cs + y1 * sn);
    }
}

// ---------------- V transpose: qkv fp32 v-part -> vT[NH][128][T] bf16 ----------------
__global__ __launch_bounds__(256) void v_transpose(const float* __restrict__ qkv,
                                                   unsigned short* __restrict__ vT) {
    __shared__ float tile[64][129];
    int t0 = blockIdx.x * 64, h = blockIdx.y, tid = threadIdx.x;
#pragma unroll 4
    for (int i = 0; i < 32; i++) {
        int e = tid + 256 * i;
        int r = e >> 7, d = e & 127;
        tile[r][d] = qkv[(size_t)(t0 + r) * NQKV + 2 * HID + h * 128 + d];
    }
    __syncthreads();
#pragma unroll 4
    for (int i = 0; i < 32; i++) {
        int e = tid + 256 * i;
        int d = e >> 6, r = e & 63;
        vT[(size_t)h * (128 * T_SEQ) + (size_t)d * T_SEQ + t0 + r] = f2b(tile[r][d]);
    }
}

// ---------------- flash attention (unchanged from round 1) ----------------
__global__ __launch_bounds__(256) void attn_kernel(const unsigned short* __restrict__ Q,
                                                   const unsigned short* __restrict__ Kb,
                                                   const unsigned short* __restrict__ Vt,
                                                   unsigned short* __restrict__ O) {
    __shared__ __align__(16) unsigned short Ktile[2][4096];
    __shared__ __align__(16) unsigned short Vtile[2][4096];

    int w = threadIdx.x >> 6, lane = threadIdx.x & 63;
    int quad = lane >> 4, cl = lane & 15;
    int h = blockIdx.x;
    int y = blockIdx.y;
    int strip = (y < 8) ? (15 - y) : (y - 8);
    int qbase = strip * 128;
    int qw0 = qbase + w * 32;
    int qmaxw = qw0 + 31;
    const float scale = 0.08838834764831845f;

    const unsigned short* Kh = Kb + h * 128;
    const unsigned short* vh = Vt + (size_t)h * (128 * T_SEQ);

    bf16x8 bq[2][4];
#pragma unroll
    for (int qh = 0; qh < 2; qh++)
#pragma unroll
        for (int s = 0; s < 4; s++)
            bq[qh][s] = *(const bf16x8*)&Q[(size_t)(qw0 + qh * 16 + cl) * HID + h * 128 + s * 32 + quad * 8];

    f32x4 o[2][8] = {};
    float m_run[2] = {-1e30f, -1e30f};
    float l_run[2] = {0.f, 0.f};

    int ntiles = strip * 4 + 4;

#define ASTAGE(b, kt2) do {                                                      \
        int kb2 = (kt2) * 32;                                                    \
        if (w < 2) {                                                             \
            _Pragma("unroll")                                                    \
            for (int i = 0; i < 4; i++) {                                        \
                int p = w * 256 + i * 64 + lane;                                 \
                int row = p >> 4;                                                \
                int c = (p & 15) ^ (row & 7);                                    \
                gld_lds16(Kh + (size_t)(kb2 + row) * HID + c * 8,                \
                          &Ktile[b][(w * 256 + i * 64) * 8]);                    \
            }                                                                    \
        } else {                                                                 \
            _Pragma("unroll")                                                    \
            for (int i = 0; i < 4; i++) {                                        \
                int p = (w - 2) * 256 + i * 64 + lane;                           \
                int d = p >> 2;                                                  \
                int c = (p & 3) ^ (d & 3);                                       \
                gld_lds16(vh + (size_t)d * T_SEQ + kb2 + c * 8,                  \
                          &Vtile[b][((w - 2) * 256 + i * 64) * 8]);              \
            }                                                                    \
        }                                                                        \
    } while (0)

    ASTAGE(0, 0);
    __syncthreads();

    int buf = 0;
    for (int kt = 0; kt < ntiles; kt++) {
        if (kt + 1 < ntiles) ASTAGE(buf ^ 1, kt + 1);
        int kb = kt * 32;
        if (kb <= qmaxw) {
            const unsigned short* Kl = Ktile[buf];
            const unsigned short* Vl = Vtile[buf];
            f32x4 sA[2][2] = {};
#pragma unroll
            for (int s = 0; s < 4; s++) {
                int swz = (((s * 4 + quad) ^ (cl & 7)) * 8);
                bf16x8 ak0 = *(const bf16x8*)&Kl[cl * 128 + swz];
                bf16x8 ak1 = *(const bf16x8*)&Kl[(16 + cl) * 128 + swz];
                sA[0][0] = mfma16(ak0, bq[0][s], sA[0][0]);
                sA[0][1] = mfma16(ak1, bq[0][s], sA[0][1]);
                sA[1][0] = mfma16(ak0, bq[1][s], sA[1][0]);
                sA[1][1] = mfma16(ak1, bq[1][s], sA[1][1]);
            }
            bf16x8 ap[2];
#pragma unroll
            for (int qh = 0; qh < 2; qh++) {
                int qrow = qw0 + qh * 16 + cl;
                float p0[4], p1[4];
                float tm = -1e30f;
#pragma unroll
                for (int r = 0; r < 4; r++) {
                    int k0i = kb + quad * 4 + r;
                    float v0 = (k0i      <= qrow) ? sA[qh][0][r] * scale : -1e30f;
                    float v1 = (k0i + 16 <= qrow) ? sA[qh][1][r] * scale : -1e30f;
                    p0[r] = v0; p1[r] = v1;
                    tm = fmaxf(tm, fmaxf(v0, v1));
                }
                tm = fmaxf(tm, __shfl_xor(tm, 16, 64));
                tm = fmaxf(tm, __shfl_xor(tm, 32, 64));
                float m_new = fmaxf(m_run[qh], tm);
                float alpha = __expf(m_run[qh] - m_new);
                float ps = 0.f;
#pragma unroll
                for (int r = 0; r < 4; r++) {
                    p0[r] = __expf(p0[r] - m_new);
                    p1[r] = __expf(p1[r] - m_new);
                    ps += p0[r] + p1[r];
                }
                ps += __shfl_xor(ps, 16, 64);
                ps += __shfl_xor(ps, 32, 64);
                l_run[qh] = l_run[qh] * alpha + ps;
                m_run[qh] = m_new;
                float ar[4];
#pragma unroll
                for (int r = 0; r < 4; r++)
                    ar[r] = __shfl(alpha, quad * 4 + r, 64);
#pragma unroll
                for (int dc = 0; dc < 8; dc++) {
                    o[qh][dc][0] *= ar[0]; o[qh][dc][1] *= ar[1];
                    o[qh][dc][2] *= ar[2]; o[qh][dc][3] *= ar[3];
                }
                unsigned int ph0[2], ph1[2];
                ph0[0] = pack2(p0[0], p0[1]); ph0[1] = pack2(p0[2], p0[3]);
                ph1[0] = pack2(p1[0], p1[1]); ph1[1] = pack2(p1[2], p1[3]);
                union { unsigned int u[4]; bf16x8 v; } apv;
#pragma unroll
                for (int i = 0; i < 4; i++) {
                    int tloc = (4 * quad + i) & 7;
                    int srcLane = ((tloc >> 1) << 4) | cl;
                    unsigned int u0 = (unsigned int)__shfl((int)ph0[i & 1], srcLane, 64);
                    unsigned int u1 = (unsigned int)__shfl((int)ph1[i & 1], srcLane, 64);
                    apv.u[i] = (quad >= 2) ? u1 : u0;
                }
                ap[qh] = apv.v;
            }
#pragma unroll
            for (int dc = 0; dc < 8; dc++) {
                int d = dc * 16 + cl;
                bf16x8 bv = *(const bf16x8*)&Vl[d * 32 + ((quad ^ (cl & 3)) * 8)];
                o[0][dc] = mfma16(ap[0], bv, o[0][dc]);
                o[1][dc] = mfma16(ap[1], bv, o[1][dc]);
            }
        }
        __syncthreads();
        buf ^= 1;
    }
#undef ASTAGE

#pragma unroll
    for (int qh = 0; qh < 2; qh++) {
        float linv[4];
#pragma unroll
        for (int r = 0; r < 4; r++)
            linv[r] = 1.f / __shfl(l_run[qh], quad * 4 + r, 64);
#pragma unroll
        for (int dc = 0; dc < 8; dc++) {
#pragma unroll
            for (int r = 0; r < 4; r++) {
                int row = qw0 + qh * 16 + quad * 4 + r;
                O[(size_t)row * HID + h * 128 + dc * 16 + cl] = f2b(o[qh][dc][r] * linv[r]);
            }
        }
    }
}

extern "C" void kernel_launch(void* const* d_in, const int* in_sizes, int n_in,
                              void* d_out, int out_size, void* d_ws, size_t ws_size,
                              hipStream_t stream) {
    const float* hs    = (const float*)d_in[0];
    const float* w_qkv = (const float*)d_in[1];
    const float* b_qkv = (const float*)d_in[2];
    const float* qw    = (const float*)d_in[3];
    const float* kw    = (const float*)d_in[4];
    const float* w_o   = (const float*)d_in[5];
    float* out = (float*)d_out;

    char* ws = (char*)d_ws;
    unsigned short* hsbf  = (unsigned short*)(ws);                 // 2048*4096*2  =  16777216
    unsigned short* wqkvT = (unsigned short*)(ws + 16777216);      // 12288*4096*2 = 100663296
    unsigned short* woT   = (unsigned short*)(ws + 117440512);     //  4096*4096*2 =  33554432
    float*          qkv   = (float*)(ws + 150994944);              //  2048*12288*4 = 100663296
    unsigned short* qbf   = (unsigned short*)(ws + 251658240);     //  16777216
    unsigned short* kbf   = (unsigned short*)(ws + 268435456);     //  16777216
    unsigned short* vT    = (unsigned short*)(ws + 285212672);     //  16777216
    unsigned short* attn  = (unsigned short*)(ws + 301989888);     //  16777216 (total ~318.8 MB)

    cast_f32_bf16<<<8192, 256, 0, stream>>>(hs, hsbf);
    transpose_f32_bf16<<<dim3(64, 192), 256, 0, stream>>>(w_qkv, wqkvT, HID, NQKV);
    transpose_f32_bf16<<<dim3(64, 64),  256, 0, stream>>>(w_o, woT, HID, HID);
    gemm256<1><<<dim3(8, 96), 512, 0, stream>>>(hsbf, wqkvT, b_qkv, qkv, NQKV, HID);
    rmsnorm_rope<<<T_SEQ, 256, 0, stream>>>(qkv, qw, kw, qbf, kbf);
    v_transpose<<<dim3(32, 32), 256, 0, stream>>>(qkv, vT);
    attn_kernel<<<dim3(32, 16), 256, 0, stream>>>(qbf, kbf, vT, attn);
    gemm256<0><<<dim3(8, 32), 512, 0, stream>>>(attn, woT, nullptr, out, HID, HID);
}

// Round 4
// 916.087 us; speedup vs baseline: 1.0918x; 1.0918x over previous
//
#include <hip/hip_runtime.h>
#include <hip/hip_bf16.h>
#include <stdint.h>

#define T_SEQ 2048
#define HID   4096
#define NQKV  12288
#define NH    32
#define HD    128

typedef __attribute__((ext_vector_type(8))) short bf16x8;
typedef __attribute__((ext_vector_type(4))) float f32x4;

__device__ __forceinline__ unsigned short f2b(float f) {
    __hip_bfloat16 h = __float2bfloat16(f);
    return *reinterpret_cast<unsigned short*>(&h);
}
__device__ __forceinline__ unsigned int pack2(float a, float b) {
    return (unsigned int)f2b(a) | ((unsigned int)f2b(b) << 16);
}
__device__ __forceinline__ f32x4 mfma16(bf16x8 a, bf16x8 b, f32x4 c) {
    return __builtin_amdgcn_mfma_f32_16x16x32_bf16(a, b, c, 0, 0, 0);
}
__device__ __forceinline__ void gld_lds16(const void* g, void* l) {
    __builtin_amdgcn_global_load_lds(
        (const __attribute__((address_space(1))) unsigned int*)g,
        (__attribute__((address_space(3))) unsigned int*)l, 16, 0, 0);
}

// ---------------- cast fp32 -> bf16, 4 elems/thread ----------------
__global__ __launch_bounds__(256) void cast_f32_bf16(const float* __restrict__ src,
                                                     unsigned short* __restrict__ dst) {
    int i = (blockIdx.x * 256 + threadIdx.x) * 4;
    float4 v = *(const float4*)(src + i);
    ushort4 o;
    o.x = f2b(v.x); o.y = f2b(v.y); o.z = f2b(v.z); o.w = f2b(v.w);
    *(ushort4*)(dst + i) = o;
}

// ---------------- transpose: src fp32 [R][C] -> dst bf16 [C][R] ----------------
__global__ __launch_bounds__(256) void transpose_f32_bf16(const float* __restrict__ src,
                                                          unsigned short* __restrict__ dst,
                                                          int R, int C) {
    __shared__ float tile[64][65];
    int r0 = blockIdx.x * 64, c0 = blockIdx.y * 64;
    int tid = threadIdx.x;
#pragma unroll
    for (int i = 0; i < 4; i++) {
        int e = (tid + 256 * i) * 4;
        int r = e >> 6, c = e & 63;
        float4 v = *(const float4*)(src + (size_t)(r0 + r) * C + c0 + c);
        tile[r][c + 0] = v.x; tile[r][c + 1] = v.y;
        tile[r][c + 2] = v.z; tile[r][c + 3] = v.w;
    }
    __syncthreads();
#pragma unroll
    for (int i = 0; i < 4; i++) {
        int e = (tid + 256 * i) * 4;
        int rr = e >> 6, cc = e & 63;
        ushort4 o;
        o.x = f2b(tile[cc + 0][rr]); o.y = f2b(tile[cc + 1][rr]);
        o.z = f2b(tile[cc + 2][rr]); o.w = f2b(tile[cc + 3][rr]);
        *(ushort4*)(dst + (size_t)(c0 + rr) * R + r0 + cc) = o;
    }
}

// ---------------- deep-pipelined GEMM: C[M=2048][N] = A @ Bt^T (+bias) ----------------
// BM=256, BN=128, BK=32. 8 waves (4M x 2N), per-wave 64x64 output (4x4 16x16x32 frags).
// Ring-3 LDS K-tile buffers (72 KB -> 2 blocks/CU for inter-block latency overlap),
// raw s_barrier (no compiler vmcnt(0) drain), counted vmcnt: prologue stages tiles 0,1;
// steady state keeps 1 tile (3 loads/thread) in flight across the barrier.
// Hazards: RAW covered by vmcnt-before-barrier (all waves' tile-t loads landed at barrier
// exit); WAR distance-1 (slot (t+2)%3 last read at t-1, reads drained pre-barrier) --
// identical ordering to the ring-4 version verified correct in round 2.
// T2: 16B-chunk XOR swizzle applied on the GLOBAL source (gld_lds dest lane-linear);
// fragment ds_read_b128 covers each 1KB region bijectively -> 0 bank conflicts (verified r2).
// T1: XCD map brow=id&7 -> each XCD keeps one 2MB A-panel in its private L2.
template <int WITH_BIAS>
__global__ __launch_bounds__(512, 4) void gemm256(const unsigned short* __restrict__ A,
                                                  const unsigned short* __restrict__ Bt,
                                                  const float* __restrict__ bias,
                                                  float* __restrict__ C,
                                                  int N, int K) {
    __shared__ __align__(16) unsigned short As[3][256 * 32];  // 48 KB
    __shared__ __align__(16) unsigned short Bs[3][128 * 32];  // 24 KB
    int tid = threadIdx.x;
    int w = tid >> 6, lane = tid & 63;
    int quad = lane >> 4, cl = lane & 15;
    int wm = w >> 1, wn = w & 1;                 // 4 x 2 wave grid
    int id = blockIdx.x + gridDim.x * blockIdx.y;
    int brow = id & 7;                           // XCD-aligned row panel
    int bcol = id >> 3;
    const unsigned short* Ablk = A + (size_t)brow * 256 * K;
    const unsigned short* Bblk = Bt + (size_t)bcol * 128 * K;
    const int NT = K >> 5;

    // fragment LDS offsets (ushort units); swizzled chunk slot is frag-uniform per lane
    int slot = quad ^ ((cl >> 1) & 3);
    int aoff[4], boff[4];
#pragma unroll
    for (int f = 0; f < 4; f++) {
        aoff[f] = (wm * 64 + f * 16 + cl) * 32 + slot * 8;
        boff[f] = (wn * 64 + f * 16 + cl) * 32 + slot * 8;
    }

    f32x4 acc[4][4] = {};

    // stage K-tile t_ into ring slot s_: A = 1024 16B chunks (2/thread), B = 512 (1/thread)
#define STAGE(t_, s_) do {                                                      \
        int k0 = (t_) * 32;                                                     \
        _Pragma("unroll")                                                       \
        for (int j = 0; j < 2; j++) {                                           \
            int p = j * 512 + w * 64 + lane;                                    \
            int row = p >> 2;                                                   \
            int g = (p & 3) ^ ((row >> 1) & 3);                                 \
            gld_lds16(Ablk + (size_t)row * K + k0 + g * 8,                      \
                      &As[s_][(j * 512 + w * 64) * 8]);                         \
        }                                                                       \
        {                                                                       \
            int p = w * 64 + lane;                                              \
            int row = p >> 2;                                                   \
            int g = (p & 3) ^ ((row >> 1) & 3);                                 \
            gld_lds16(Bblk + (size_t)row * K + k0 + g * 8,                      \
                      &Bs[s_][(w * 64) * 8]);                                   \
        }                                                                       \
    } while (0)

    STAGE(0, 0);
    STAGE(1, 1);

    int cs = 0;                                  // ring slot of tile t
    for (int t = 0; t < NT; t++) {
        if (t < NT - 1) asm volatile("s_waitcnt vmcnt(3)" ::: "memory");  // retire tile t
        else            asm volatile("s_waitcnt vmcnt(0)" ::: "memory");
        __builtin_amdgcn_s_barrier();            // slot (t+2)%3 fully consumed by all waves
        if (t + 2 < NT) {
            int ss = (cs >= 1) ? cs - 1 : 2;     // (cs+2)%3
            STAGE(t + 2, ss);
        }
        const unsigned short* Ab = &As[cs][0];
        const unsigned short* Bb = &Bs[cs][0];
        bf16x8 af[4], bfv[4];
#pragma unroll
        for (int f = 0; f < 4; f++) af[f] = *(const bf16x8*)&Ab[aoff[f]];
#pragma unroll
        for (int f = 0; f < 4; f++) bfv[f] = *(const bf16x8*)&Bb[boff[f]];
        __builtin_amdgcn_s_setprio(1);
#pragma unroll
        for (int fi = 0; fi < 4; fi++)
#pragma unroll
            for (int fj = 0; fj < 4; fj++)
                acc[fi][fj] = mfma16(af[fi], bfv[fj], acc[fi][fj]);
        __builtin_amdgcn_s_setprio(0);
        cs = (cs == 2) ? 0 : cs + 1;
    }
#undef STAGE

    // epilogue: C/D frag layout col=cl, row=quad*4+r
#pragma unroll
    for (int fi = 0; fi < 4; fi++) {
        int row0 = brow * 256 + wm * 64 + fi * 16 + quad * 4;
#pragma unroll
        for (int fj = 0; fj < 4; fj++) {
            int col = bcol * 128 + wn * 64 + fj * 16 + cl;
            float bv = WITH_BIAS ? bias[col] : 0.f;
#pragma unroll
            for (int r = 0; r < 4; r++)
                C[(size_t)(row0 + r) * N + col] = acc[fi][fj][r] + bv;
        }
    }
}

// ---------------- RMSNorm (full 4096-dim) + RoPE -> bf16 q,k ----------------
__global__ __launch_bounds__(256) void rmsnorm_rope(const float* __restrict__ qkv,
                                                    const float* __restrict__ qw,
                                                    const float* __restrict__ kw,
                                                    unsigned short* __restrict__ qo,
                                                    unsigned short* __restrict__ ko) {
    int t = blockIdx.x, tid = threadIdx.x;
    const float* row = qkv + (size_t)t * NQKV;
    float sq = 0.f, sk = 0.f;
    for (int i = tid; i < HID; i += 256) {
        float x = row[i];        sq += x * x;
        float y = row[HID + i];  sk += y * y;
    }
#pragma unroll
    for (int off = 32; off > 0; off >>= 1) {
        sq += __shfl_xor(sq, off, 64);
        sk += __shfl_xor(sk, off, 64);
    }
    __shared__ float red[2][4];
    if ((tid & 63) == 0) { red[0][tid >> 6] = sq; red[1][tid >> 6] = sk; }
    __syncthreads();
    sq = red[0][0] + red[0][1] + red[0][2] + red[0][3];
    sk = red[1][0] + red[1][1] + red[1][2] + red[1][3];
    float rq = rsqrtf(sq * (1.0f / HID) + 1e-6f);
    float rk = rsqrtf(sk * (1.0f / HID) + 1e-6f);
    for (int p = tid; p < 2048; p += 256) {
        int h = p >> 6, d = p & 63;
        int c1 = h * 128 + d, c2 = c1 + 64;
        float inv = expf(-(float)d * 0.2158673524681918f);
        float ang = (float)t * inv;
        float sn, cs;
        sincosf(ang, &sn, &cs);
        float x1 = row[c1] * rq * qw[c1];
        float x2 = row[c2] * rq * qw[c2];
        qo[(size_t)t * HID + c1] = f2b(x1 * cs - x2 * sn);
        qo[(size_t)t * HID + c2] = f2b(x2 * cs + x1 * sn);
        float y1 = row[HID + c1] * rk * kw[c1];
        float y2 = row[HID + c2] * rk * kw[c2];
        ko[(size_t)t * HID + c1] = f2b(y1 * cs - y2 * sn);
        ko[(size_t)t * HID + c2] = f2b(y2 * cs + y1 * sn);
    }
}

// ---------------- V transpose: qkv fp32 v-part -> vT[NH][128][T] bf16 ----------------
__global__ __launch_bounds__(256) void v_transpose(const float* __restrict__ qkv,
                                                   unsigned short* __restrict__ vT) {
    __shared__ float tile[64][129];
    int t0 = blockIdx.x * 64, h = blockIdx.y, tid = threadIdx.x;
#pragma unroll 4
    for (int i = 0; i < 32; i++) {
        int e = tid + 256 * i;
        int r = e >> 7, d = e & 127;
        tile[r][d] = qkv[(size_t)(t0 + r) * NQKV + 2 * HID + h * 128 + d];
    }
    __syncthreads();
#pragma unroll 4
    for (int i = 0; i < 32; i++) {
        int e = tid + 256 * i;
        int d = e >> 6, r = e & 63;
        vT[(size_t)h * (128 * T_SEQ) + (size_t)d * T_SEQ + t0 + r] = f2b(tile[r][d]);
    }
}

// ---------------- flash attention (unchanged) ----------------
__global__ __launch_bounds__(256) void attn_kernel(const unsigned short* __restrict__ Q,
                                                   const unsigned short* __restrict__ Kb,
                                                   const unsigned short* __restrict__ Vt,
                                                   unsigned short* __restrict__ O) {
    __shared__ __align__(16) unsigned short Ktile[2][4096];
    __shared__ __align__(16) unsigned short Vtile[2][4096];

    int w = threadIdx.x >> 6, lane = threadIdx.x & 63;
    int quad = lane >> 4, cl = lane & 15;
    int h = blockIdx.x;
    int y = blockIdx.y;
    int strip = (y < 8) ? (15 - y) : (y - 8);
    int qbase = strip * 128;
    int qw0 = qbase + w * 32;
    int qmaxw = qw0 + 31;
    const float scale = 0.08838834764831845f;

    const unsigned short* Kh = Kb + h * 128;
    const unsigned short* vh = Vt + (size_t)h * (128 * T_SEQ);

    bf16x8 bq[2][4];
#pragma unroll
    for (int qh = 0; qh < 2; qh++)
#pragma unroll
        for (int s = 0; s < 4; s++)
            bq[qh][s] = *(const bf16x8*)&Q[(size_t)(qw0 + qh * 16 + cl) * HID + h * 128 + s * 32 + quad * 8];

    f32x4 o[2][8] = {};
    float m_run[2] = {-1e30f, -1e30f};
    float l_run[2] = {0.f, 0.f};

    int ntiles = strip * 4 + 4;

#define ASTAGE(b, kt2) do {                                                      \
        int kb2 = (kt2) * 32;                                                    \
        if (w < 2) {                                                             \
            _Pragma("unroll")                                                    \
            for (int i = 0; i < 4; i++) {                                        \
                int p = w * 256 + i * 64 + lane;                                 \
                int row = p >> 4;                                                \
                int c = (p & 15) ^ (row & 7);                                    \
                gld_lds16(Kh + (size_t)(kb2 + row) * HID + c * 8,                \
                          &Ktile[b][(w * 256 + i * 64) * 8]);                    \
            }                                                                    \
        } else {                                                                 \
            _Pragma("unroll")                                                    \
            for (int i = 0; i < 4; i++) {                                        \
                int p = (w - 2) * 256 + i * 64 + lane;                           \
                int d = p >> 2;                                                  \
                int c = (p & 3) ^ (d & 3);                                       \
                gld_lds16(vh + (size_t)d * T_SEQ + kb2 + c * 8,                  \
                          &Vtile[b][((w - 2) * 256 + i * 64) * 8]);              \
            }                                                                    \
        }                                                                        \
    } while (0)

    ASTAGE(0, 0);
    __syncthreads();

    int buf = 0;
    for (int kt = 0; kt < ntiles; kt++) {
        if (kt + 1 < ntiles) ASTAGE(buf ^ 1, kt + 1);
        int kb = kt * 32;
        if (kb <= qmaxw) {
            const unsigned short* Kl = Ktile[buf];
            const unsigned short* Vl = Vtile[buf];
            f32x4 sA[2][2] = {};
#pragma unroll
            for (int s = 0; s < 4; s++) {
                int swz = (((s * 4 + quad) ^ (cl & 7)) * 8);
                bf16x8 ak0 = *(const bf16x8*)&Kl[cl * 128 + swz];
                bf16x8 ak1 = *(const bf16x8*)&Kl[(16 + cl) * 128 + swz];
                sA[0][0] = mfma16(ak0, bq[0][s], sA[0][0]);
                sA[0][1] = mfma16(ak1, bq[0][s], sA[0][1]);
                sA[1][0] = mfma16(ak0, bq[1][s], sA[1][0]);
                sA[1][1] = mfma16(ak1, bq[1][s], sA[1][1]);
            }
            bf16x8 ap[2];
#pragma unroll
            for (int qh = 0; qh < 2; qh++) {
                int qrow = qw0 + qh * 16 + cl;
                float p0[4], p1[4];
                float tm = -1e30f;
#pragma unroll
                for (int r = 0; r < 4; r++) {
                    int k0i = kb + quad * 4 + r;
                    float v0 = (k0i      <= qrow) ? sA[qh][0][r] * scale : -1e30f;
                    float v1 = (k0i + 16 <= qrow) ? sA[qh][1][r] * scale : -1e30f;
                    p0[r] = v0; p1[r] = v1;
                    tm = fmaxf(tm, fmaxf(v0, v1));
                }
                tm = fmaxf(tm, __shfl_xor(tm, 16, 64));
                tm = fmaxf(tm, __shfl_xor(tm, 32, 64));
                float m_new = fmaxf(m_run[qh], tm);
                float alpha = __expf(m_run[qh] - m_new);
                float ps = 0.f;
#pragma unroll
                for (int r = 0; r < 4; r++) {
                    p0[r] = __expf(p0[r] - m_new);
                    p1[r] = __expf(p1[r] - m_new);
                    ps += p0[r] + p1[r];
                }
                ps += __shfl_xor(ps, 16, 64);
                ps += __shfl_xor(ps, 32, 64);
                l_run[qh] = l_run[qh] * alpha + ps;
                m_run[qh] = m_new;
                float ar[4];
#pragma unroll
                for (int r = 0; r < 4; r++)
                    ar[r] = __shfl(alpha, quad * 4 + r, 64);
#pragma unroll
                for (int dc = 0; dc < 8; dc++) {
                    o[qh][dc][0] *= ar[0]; o[qh][dc][1] *= ar[1];
                    o[qh][dc][2] *= ar[2]; o[qh][dc][3] *= ar[3];
                }
                unsigned int ph0[2], ph1[2];
                ph0[0] = pack2(p0[0], p0[1]); ph0[1] = pack2(p0[2], p0[3]);
                ph1[0] = pack2(p1[0], p1[1]); ph1[1] = pack2(p1[2], p1[3]);
                union { unsigned int u[4]; bf16x8 v; } apv;
#pragma unroll
                for (int i = 0; i < 4; i++) {
                    int tloc = (4 * quad + i) & 7;
                    int srcLane = ((tloc >> 1) << 4) | cl;
                    unsigned int u0 = (unsigned int)__shfl((int)ph0[i & 1], srcLane, 64);
                    unsigned int u1 = (unsigned int)__shfl((int)ph1[i & 1], srcLane, 64);
                    apv.u[i] = (quad >= 2) ? u1 : u0;
                }
                ap[qh] = apv.v;
            }
#pragma unroll
            for (int dc = 0; dc < 8; dc++) {
                int d = dc * 16 + cl;
                bf16x8 bv = *(const bf16x8*)&Vl[d * 32 + ((quad ^ (cl & 3)) * 8)];
                o[0][dc] = mfma16(ap[0], bv, o[0][dc]);
                o[1][dc] = mfma16(ap[1], bv, o[1][dc]);
            }
        }
        __syncthreads();
        buf ^= 1;
    }
#undef ASTAGE

#pragma unroll
    for (int qh = 0; qh < 2; qh++) {
        float linv[4];
#pragma unroll
        for (int r = 0; r < 4; r++)
            linv[r] = 1.f / __shfl(l_run[qh], quad * 4 + r, 64);
#pragma unroll
        for (int dc = 0; dc < 8; dc++) {
#pragma unroll
            for (int r = 0; r < 4; r++) {
                int row = qw0 + qh * 16 + quad * 4 + r;
                O[(size_t)row * HID + h * 128 + dc * 16 + cl] = f2b(o[qh][dc][r] * linv[r]);
            }
        }
    }
}

extern "C" void kernel_launch(void* const* d_in, const int* in_sizes, int n_in,
                              void* d_out, int out_size, void* d_ws, size_t ws_size,
                              hipStream_t stream) {
    const float* hs    = (const float*)d_in[0];
    const float* w_qkv = (const float*)d_in[1];
    const float* b_qkv = (const float*)d_in[2];
    const float* qw    = (const float*)d_in[3];
    const float* kw    = (const float*)d_in[4];
    const float* w_o   = (const float*)d_in[5];
    float* out = (float*)d_out;

    char* ws = (char*)d_ws;
    unsigned short* hsbf  = (unsigned short*)(ws);                 // 2048*4096*2  =  16777216
    unsigned short* wqkvT = (unsigned short*)(ws + 16777216);      // 12288*4096*2 = 100663296
    unsigned short* woT   = (unsigned short*)(ws + 117440512);     //  4096*4096*2 =  33554432
    float*          qkv   = (float*)(ws + 150994944);              //  2048*12288*4 = 100663296
    unsigned short* qbf   = (unsigned short*)(ws + 251658240);     //  16777216
    unsigned short* kbf   = (unsigned short*)(ws + 268435456);     //  16777216
    unsigned short* vT    = (unsigned short*)(ws + 285212672);     //  16777216
    unsigned short* attn  = (unsigned short*)(ws + 301989888);     //  16777216 (total ~318.8 MB)

    cast_f32_bf16<<<8192, 256, 0, stream>>>(hs, hsbf);
    transpose_f32_bf16<<<dim3(64, 192), 256, 0, stream>>>(w_qkv, wqkvT, HID, NQKV);
    transpose_f32_bf16<<<dim3(64, 64),  256, 0, stream>>>(w_o, woT, HID, HID);
    gemm256<1><<<dim3(8, 96), 512, 0, stream>>>(hsbf, wqkvT, b_qkv, qkv, NQKV, HID);
    rmsnorm_rope<<<T_SEQ, 256, 0, stream>>>(qkv, qw, kw, qbf, kbf);
    v_transpose<<<dim3(32, 32), 256, 0, stream>>>(qkv, vT);
    attn_kernel<<<dim3(32, 16), 256, 0, stream>>>(qbf, kbf, vT, attn);
    gemm256<0><<<dim3(8, 32), 512, 0, stream>>>(attn, woT, nullptr, out, HID, HID);
}